// Round 6
// baseline (737.103 us; speedup 1.0000x reference)
//
#include <hip/hip_runtime.h>
#include <math.h>

#define N_PTS 8192
#define D_FEAT 768

// ---- wave64 reductions via DPP (row_shr 1,2,4,8 + row_bcast15, row_bcast31) ----
__device__ __forceinline__ float wred_max_f32(float x) {   // x >= 0 required (identity 0)
    int v = __float_as_int(x), o;
    o = __builtin_amdgcn_update_dpp(0, v, 0x111, 0xf, 0xf, false); v = __float_as_int(fmaxf(__int_as_float(v), __int_as_float(o)));
    o = __builtin_amdgcn_update_dpp(0, v, 0x112, 0xf, 0xf, false); v = __float_as_int(fmaxf(__int_as_float(v), __int_as_float(o)));
    o = __builtin_amdgcn_update_dpp(0, v, 0x114, 0xf, 0xf, false); v = __float_as_int(fmaxf(__int_as_float(v), __int_as_float(o)));
    o = __builtin_amdgcn_update_dpp(0, v, 0x118, 0xf, 0xf, false); v = __float_as_int(fmaxf(__int_as_float(v), __int_as_float(o)));
    o = __builtin_amdgcn_update_dpp(0, v, 0x142, 0xa, 0xf, false); v = __float_as_int(fmaxf(__int_as_float(v), __int_as_float(o)));
    o = __builtin_amdgcn_update_dpp(0, v, 0x143, 0xc, 0xf, false); v = __float_as_int(fmaxf(__int_as_float(v), __int_as_float(o)));
    return __int_as_float(__builtin_amdgcn_readlane(v, 63));
}
__device__ __forceinline__ int wred_min_i32(int x) {       // x >= 0 (identity INT_MAX)
    int v = x, o;
    o = __builtin_amdgcn_update_dpp(0x7fffffff, v, 0x111, 0xf, 0xf, false); v = (o < v) ? o : v;
    o = __builtin_amdgcn_update_dpp(0x7fffffff, v, 0x112, 0xf, 0xf, false); v = (o < v) ? o : v;
    o = __builtin_amdgcn_update_dpp(0x7fffffff, v, 0x114, 0xf, 0xf, false); v = (o < v) ? o : v;
    o = __builtin_amdgcn_update_dpp(0x7fffffff, v, 0x118, 0xf, 0xf, false); v = (o < v) ? o : v;
    o = __builtin_amdgcn_update_dpp(0x7fffffff, v, 0x142, 0xa, 0xf, false); v = (o < v) ? o : v;
    o = __builtin_amdgcn_update_dpp(0x7fffffff, v, 0x143, 0xc, 0xf, false); v = (o < v) ? o : v;
    return __builtin_amdgcn_readlane(v, 63);
}
__device__ __forceinline__ float wred_add_f32(float x) {   // identity 0
    int v = __float_as_int(x), o;
    o = __builtin_amdgcn_update_dpp(0, v, 0x111, 0xf, 0xf, false); v = __float_as_int(__int_as_float(v) + __int_as_float(o));
    o = __builtin_amdgcn_update_dpp(0, v, 0x112, 0xf, 0xf, false); v = __float_as_int(__int_as_float(v) + __int_as_float(o));
    o = __builtin_amdgcn_update_dpp(0, v, 0x114, 0xf, 0xf, false); v = __float_as_int(__int_as_float(v) + __int_as_float(o));
    o = __builtin_amdgcn_update_dpp(0, v, 0x118, 0xf, 0xf, false); v = __float_as_int(__int_as_float(v) + __int_as_float(o));
    o = __builtin_amdgcn_update_dpp(0, v, 0x142, 0xa, 0xf, false); v = __float_as_int(__int_as_float(v) + __int_as_float(o));
    o = __builtin_amdgcn_update_dpp(0, v, 0x143, 0xc, 0xf, false); v = __float_as_int(__int_as_float(v) + __int_as_float(o));
    return __int_as_float(__builtin_amdgcn_readlane(v, 63));
}

// u64 max-merge DPP step on (hi,lo) pair. identity (0,0) loses to any real key.
#define DPP64_MAX_STEP(ctrl, rmask)                                                       \
    {                                                                                     \
        unsigned ohi = (unsigned)__builtin_amdgcn_update_dpp(0, (int)hi, ctrl, rmask, 0xf, false); \
        unsigned olo = (unsigned)__builtin_amdgcn_update_dpp(0, (int)lo, ctrl, rmask, 0xf, false); \
        bool gt = (ohi > hi) || ((ohi == hi) && (olo > lo));                              \
        hi = gt ? ohi : hi;                                                               \
        lo = gt ? olo : lo;                                                               \
    }

// ---------------- FPS + global/component safety: one block per batch ----------------
// KEY CHANGE vs round 5: the iteration loop touches NO global memory. Global
// stores before s_barrier force a full vmcnt(0) drain every iteration (compiler
// emits s_waitcnt vmcnt(0) lgkmcnt(0) before s_barrier); og/oc/od in-loop writes
// were stalling all 8 waves ~600-900 cyc/iter. Indices accumulate in sel[] (LDS)
// and are written to global once at the tail.
__global__ __launch_bounds__(512, 1) void fps_kernel(const float* __restrict__ coords,
                                                     int* __restrict__ idx_all,
                                                     float* __restrict__ safety_all) {
#pragma clang fp contract(off)
    const int b = blockIdx.x;         // 0..1
    const int t = threadIdx.x;
    const float* cb = coords + (size_t)b * N_PTS * 3;

    float px[16], py[16], pz[16], m2[16];
#pragma unroll
    for (int k = 0; k < 16; k++) {
        int p = t + k * 512;
        px[k] = cb[p * 3 + 0];
        py[k] = cb[p * 3 + 1];
        pz[k] = cb[p * 3 + 2];
        m2[k] = INFINITY;
    }
    __shared__ unsigned long long skey[2][8];
    __shared__ float scw[2][24];      // per-wave candidate coords, flattened w*3+c
    __shared__ int sel[256];
    __shared__ float r1s[8], r2s[8];
    if (t == 0) sel[0] = 0;
    float lx = cb[0], ly = cb[1], lz = cb[2];   // center 0 (uniform broadcast load)
    __syncthreads();

    const int lane = t & 63, w = t >> 6;
    for (int i = 1; i < 256; i++) {
        // --- branch-free d2-domain update: 9 VALU/k, fully pipelineable ---
#pragma unroll
        for (int k = 0; k < 16; k++) {
            float dx = px[k] - lx, dy = py[k] - ly, dz = pz[k] - lz;
            float d2 = dx * dx + dy * dy + dz * dz;   // contract off: numpy op order
            m2[k] = fminf(m2[k], d2);
        }
        // --- per-thread argmax (value + first index), d2 domain ---
        float c2 = m2[0]; int bk = 0;
#pragma unroll
        for (int k = 1; k < 16; k++) if (m2[k] > c2) { c2 = m2[k]; bk = k; }
        // sqrt-collapse guard: if >=2 entries within relative 5e-7 of c2, their
        // rounded sqrts could tie -> exact path. Band > 2*ulp(sqrt) + slop, so
        // outside the band strict d2 order == strict sqrt order.
        int ncnt = 0;
#pragma unroll
        for (int k = 0; k < 16; k++) ncnt += (m2[k] >= c2 * 0.9999995f) ? 1 : 0;
        float smax;
        if (__any(ncnt >= 2)) {       // rare wave-uniform slow path (exact)
            float sd[16];
#pragma unroll
            for (int k = 0; k < 16; k++) sd[k] = sqrtf(m2[k]);
            smax = sd[0]; bk = 0;
#pragma unroll
            for (int k = 1; k < 16; k++) if (sd[k] > smax) { smax = sd[k]; bk = k; }
        } else {
            smax = sqrtf(c2);         // one correctly-rounded sqrt per thread
        }
        int bi = t + bk * 512;
        // --- wave reduce on packed u64 key: (value desc, index asc) ---
        unsigned hi = __float_as_uint(smax);
        unsigned lo = 0xFFFFFFFFu - (unsigned)bi;
        DPP64_MAX_STEP(0x111, 0xf)    // row_shr1
        DPP64_MAX_STEP(0x112, 0xf)    // row_shr2
        DPP64_MAX_STEP(0x114, 0xf)    // row_shr4
        DPP64_MAX_STEP(0x118, 0xf)    // row_shr8
        DPP64_MAX_STEP(0x142, 0xa)    // row_bcast15
        DPP64_MAX_STEP(0x143, 0xc)    // row_bcast31
        unsigned whi = (unsigned)__builtin_amdgcn_readlane((int)hi, 63);
        unsigned wlo = (unsigned)__builtin_amdgcn_readlane((int)lo, 63);
        if (lane == 0) skey[i & 1][w] = ((unsigned long long)whi << 32) | wlo;
        int wcand = (int)(0xFFFFFFFFu - wlo);
        if (t == (wcand & 511)) {     // wave-candidate owner stashes its coords
            int kk = wcand >> 9;
            float wx = 0.f, wy = 0.f, wz = 0.f;
#pragma unroll
            for (int k = 0; k < 16; k++) if (k == kk) { wx = px[k]; wy = py[k]; wz = pz[k]; }
            scw[i & 1][w * 3 + 0] = wx;
            scw[i & 1][w * 3 + 1] = wy;
            scw[i & 1][w * 3 + 2] = wz;
        }
        __syncthreads();   // LDS-only traffic before this barrier -> cheap drain
        const int par = i & 1;
        // --- lane-parallel block combine: 1 ds_read_b64 + 3 DPP steps ---
        unsigned long long k8 = skey[par][lane & 7];
        {
            unsigned hi = (unsigned)(k8 >> 32), lo = (unsigned)k8;
            DPP64_MAX_STEP(0x111, 0xf)
            DPP64_MAX_STEP(0x112, 0xf)
            DPP64_MAX_STEP(0x114, 0xf)   // lane 7 now holds max of keys 0..7
            k8 = ((unsigned long long)(unsigned)__builtin_amdgcn_readlane((int)hi, 7) << 32)
               | (unsigned)__builtin_amdgcn_readlane((int)lo, 7);
        }
        int fbi = (int)(0xFFFFFFFFu - (unsigned)(k8 & 0xFFFFFFFFu));
        int ww = (fbi & 511) >> 6;
        // coords: all 24 stash floats were loaded lane-parallel; pick via readlane
        float cval = scw[par][lane < 24 ? lane : 0];
        lx = __int_as_float(__builtin_amdgcn_readlane(__float_as_int(cval), 3 * ww + 0));
        ly = __int_as_float(__builtin_amdgcn_readlane(__float_as_int(cval), 3 * ww + 1));
        lz = __int_as_float(__builtin_amdgcn_readlane(__float_as_int(cval), 3 * ww + 2));
        if (t == (fbi & 511)) {       // zero the picked point (no dynamic reg index)
#pragma unroll
            for (int k = 0; k < 16; k++) if (fbi == t + k * 512) m2[k] = 0.f;
        }
        if (t == 0) sel[i] = fbi;     // LDS only — no global store in the loop
    }

    // ---- tail: write indices once (oc/od are prefixes of og) ----
    __syncthreads();
    if (t < 256) {
        int v = sel[t];
        idx_all[b * 256 + t] = v;                    // og
        if (t < 128) idx_all[512 + b * 128 + t] = v; // oc
        if (t < 64)  idx_all[768 + b * 64 + t] = v;  // od
    }

    // ---- tail: global & component safety (z already in registers) ----
    float s1 = 0.f, s2 = 0.f;
#pragma unroll
    for (int k = 0; k < 16; k++) { s1 += pz[k]; s2 += pz[k] * pz[k]; }
    s1 = wred_add_f32(s1);
    s2 = wred_add_f32(s2);
    if (lane == 0) { r1s[w] = s1; r2s[w] = s2; }
    __syncthreads();
    float S1 = 0.f, S2 = 0.f;
#pragma unroll
    for (int w2 = 0; w2 < 8; w2++) { S1 += r1s[w2]; S2 += r2s[w2]; }
    float mean = S1 / 8192.0f;
    float var1 = (S2 - S1 * S1 / 8192.0f) / 8191.0f;     // ddof=1
    float scomp = 1.0f + expf(-var1 / 0.1f) * 0.9f;      // component safety
    if (t < 256) {
        int p = sel[t];
        float z = cb[p * 3 + 2];
        safety_all[b * 256 + t] = 1.0f + (1.0f / (1.0f + expf(-((z - mean) / 5.0f)))) * 0.95f;
    }
    if (t < 128) safety_all[512 + b * 128 + t] = scomp;
}

// ---------------- per-scale score MLP (+ detail density folded in) ----------------
__global__ __launch_bounds__(256) void score_kernel(
    const float* __restrict__ feat, const float* __restrict__ coords,
    const float* __restrict__ gW1, const float* __restrict__ gb1,
    const float* __restrict__ gW2, const float* __restrict__ gb2,
    const float* __restrict__ cW1, const float* __restrict__ cb1,
    const float* __restrict__ cW2, const float* __restrict__ cb2,
    const float* __restrict__ dW1, const float* __restrict__ db1,
    const float* __restrict__ dW2, const float* __restrict__ db2,
    const int* __restrict__ idx_all, const float* __restrict__ safety_all,
    float* __restrict__ final_all) {
    int bid = blockIdx.x;
    int b, c0, C, S, off;
    const float *W1, *b1, *W2, *b2;
    if (bid < 64)      { C = 256; S = 16; W1 = gW1; b1 = gb1; W2 = gW2; b2 = gb2; b = bid >> 5; c0 = (bid & 31) * 8; off = 0; }
    else if (bid < 96) { int r = bid - 64; C = 128; S = 16; W1 = cW1; b1 = cb1; W2 = cW2; b2 = cb2; b = r >> 4; c0 = (r & 15) * 8; off = 512; }
    else               { int r = bid - 96; C = 64;  S = 8;  W1 = dW1; b1 = db1; W2 = dW2; b2 = db2; b = r >> 3; c0 = (r & 7) * 8; off = 768; }
    const bool isdet = (bid >= 96);

    __shared__ float xt[8 * 772];
    __shared__ float h1s[8 * 260];
    __shared__ float ps[8 * 16];
    __shared__ int pid[8];
    __shared__ float dpart[4][8];
    __shared__ float sdens[8];
    const int t = threadIdx.x;
    if (t < 8) pid[t] = idx_all[off + b * C + c0 + t];
    __syncthreads();

    if (isdet) {
#pragma clang fp contract(off)
        float cx[8], cy[8], cz[8], cc[8];
#pragma unroll
        for (int c = 0; c < 8; c++) {
            const float* cp = coords + ((size_t)b * N_PTS + pid[c]) * 3;
            cx[c] = cp[0]; cy[c] = cp[1]; cz[c] = cp[2];
            cc[c] = cx[c] * cx[c] + cy[c] * cy[c] + cz[c] * cz[c];
        }
        int cnt[8];
#pragma unroll
        for (int c = 0; c < 8; c++) cnt[c] = 0;
        const float* cbl = coords + (size_t)b * N_PTS * 3;
        for (int k = 0; k < 32; k++) {
            int q = t + k * 256;
            float x = cbl[q * 3], y = cbl[q * 3 + 1], z = cbl[q * 3 + 2];
            float pp = x * x + y * y + z * z;
#pragma unroll
            for (int c = 0; c < 8; c++) {
                float dot = cx[c] * x + cy[c] * y + cz[c] * z;
                float d2 = (cc[c] + pp) - 2.0f * dot;   // same formula/order as reference
                if (d2 < 0.25f) cnt[c]++;
            }
        }
        int wv = t >> 6;
#pragma unroll
        for (int c = 0; c < 8; c++) {
            float s = wred_add_f32((float)cnt[c]);      // integer counts: exact in f32
            if ((t & 63) == 0) dpart[wv][c] = s;
        }
    }

    for (int r = 0; r < 8; r++) {
        const float* src = feat + ((size_t)b * N_PTS + pid[r]) * D_FEAT;
        for (int c = t; c < 768; c += 256) xt[r * 772 + c] = src[c];
    }
    __syncthreads();
    if (isdet && t < 8) {
        float tot = dpart[0][t] + dpart[1][t] + dpart[2][t] + dpart[3][t];
        sdens[t] = 1.0f + (tot / 8192.0f) * 0.95f;
    }

    {
        int rp = t & 3;
        int jg = t >> 2;
        int r0 = rp * 2;
        if (jg * 4 < C) {
            float4 acc0[4], acc1[4];
#pragma unroll
            for (int a = 0; a < 4; a++) { acc0[a] = make_float4(0, 0, 0, 0); acc1[a] = make_float4(0, 0, 0, 0); }
            for (int k = 0; k < 768; k += 4) {
                float4 x0 = *(const float4*)&xt[r0 * 772 + k];
                float4 x1 = *(const float4*)&xt[(r0 + 1) * 772 + k];
#pragma unroll
                for (int a = 0; a < 4; a++) {
                    int j = jg * 4 + a;
                    float4 wv = *(const float4*)&W1[(size_t)j * 768 + k];
                    acc0[a].x = fmaf(wv.x, x0.x, acc0[a].x); acc0[a].y = fmaf(wv.y, x0.y, acc0[a].y);
                    acc0[a].z = fmaf(wv.z, x0.z, acc0[a].z); acc0[a].w = fmaf(wv.w, x0.w, acc0[a].w);
                    acc1[a].x = fmaf(wv.x, x1.x, acc1[a].x); acc1[a].y = fmaf(wv.y, x1.y, acc1[a].y);
                    acc1[a].z = fmaf(wv.z, x1.z, acc1[a].z); acc1[a].w = fmaf(wv.w, x1.w, acc1[a].w);
                }
            }
#pragma unroll
            for (int a = 0; a < 4; a++) {
                int j = jg * 4 + a;
                float bb = b1[j];
                float v0 = (acc0[a].x + acc0[a].y) + (acc0[a].z + acc0[a].w) + bb;
                float v1 = (acc1[a].x + acc1[a].y) + (acc1[a].z + acc1[a].w) + bb;
                h1s[r0 * 260 + j]       = fmaxf(v0, 0.f);
                h1s[(r0 + 1) * 260 + j] = fmaxf(v1, 0.f);
            }
        }
    }
    __syncthreads();

    if (t < 8 * S) {
        int r = t / S, s = t % S;
        float4 a = make_float4(0, 0, 0, 0);
        for (int k = 0; k < C; k += 4) {
            float4 wv = *(const float4*)&W2[s * C + k];
            float4 h = *(const float4*)&h1s[r * 260 + k];
            a.x = fmaf(wv.x, h.x, a.x); a.y = fmaf(wv.y, h.y, a.y);
            a.z = fmaf(wv.z, h.z, a.z); a.w = fmaf(wv.w, h.w, a.w);
        }
        float logit = (a.x + a.y) + (a.z + a.w) + b2[s];
        ps[r * 16 + s] = 1.0f / (1.0f + expf(-logit));
    }
    __syncthreads();
    if (t < 8) {
        float m = 0.f;
        for (int s = 0; s < S; s++) m += ps[t * 16 + s];
        m /= (float)S;
        float saf = isdet ? sdens[t] : safety_all[off + b * C + c0 + t];
        final_all[off + b * C + c0 + t] = m * saf;
    }
}

// ---------------- final MLP + LayerNorm, with per-block redundant top-k ----------------
__global__ __launch_bounds__(256) void final_kernel(
    const float* __restrict__ feat, const int* __restrict__ idx_all,
    const float* __restrict__ final_all,
    const float* __restrict__ pW1, const float* __restrict__ pb1,
    const float* __restrict__ pW2, const float* __restrict__ pb2,
    const float* __restrict__ lng, const float* __restrict__ lnb,
    float* __restrict__ out) {
    int bid = blockIdx.x;               // 40 blocks
    int b = bid / 20, pr = bid % 20;
    int t = threadIdx.x;
    __shared__ float xt[2 * 772];
    __shared__ float h1s[2 * 388];
    __shared__ float red[16];
    __shared__ int tokp[2];

    int scale = (pr < 8) ? 0 : (pr < 16) ? 1 : 2;
    int C    = (scale == 0) ? 256 : (scale == 1) ? 128 : 64;
    int off  = (scale == 0) ? 0 : (scale == 1) ? 512 : 768;
    int base = (scale == 0) ? 0 : (scale == 1) ? 8 : 16;   // in block units
    int r0 = (pr - base) * 2;           // rank of first token within scale

    if (t < 64) {                       // wave 0 does the top-k
        float v[4];
#pragma unroll
        for (int j = 0; j < 4; j++) {
            int ii = t + j * 64;
            v[j] = (ii < C) ? final_all[off + b * C + ii] : -INFINITY;
        }
        for (int s = 0; s <= r0 + 1; s++) {
            float bd = v[0]; int bj = 0;
#pragma unroll
            for (int j = 1; j < 4; j++) if (v[j] > bd) { bd = v[j]; bj = j; }
            int bi2 = t + bj * 64;
            float m = wred_max_f32(bd);          // scores > 0, identity 0 safe
            int cand = (bd == m) ? bi2 : 0x7fffffff;
            int wi = wred_min_i32(cand);         // first-index tie-break = lax.top_k
            if (t == (wi & 63)) {
#pragma unroll
                for (int j = 0; j < 4; j++) if (j == (wi >> 6)) v[j] = -INFINITY;
            }
            if (t == 0) {
                if (s == r0)     tokp[0] = idx_all[off + b * C + wi];
                if (s == r0 + 1) tokp[1] = idx_all[off + b * C + wi];
            }
        }
    }
    __syncthreads();

    for (int r = 0; r < 2; r++) {
        int p = tokp[r];
        const float* src = feat + ((size_t)b * N_PTS + p) * D_FEAT;
        for (int c = t; c < 768; c += 256) xt[r * 772 + c] = src[c];
    }
    __syncthreads();

    for (int u = t; u < 768; u += 256) {
        int j = u >> 1, r = u & 1;
        float4 a = make_float4(0, 0, 0, 0);
        for (int k = 0; k < 768; k += 4) {
            float4 wv = *(const float4*)&pW1[(size_t)j * 768 + k];
            float4 x = *(const float4*)&xt[r * 772 + k];
            a.x = fmaf(wv.x, x.x, a.x); a.y = fmaf(wv.y, x.y, a.y);
            a.z = fmaf(wv.z, x.z, a.z); a.w = fmaf(wv.w, x.w, a.w);
        }
        float v = (a.x + a.y) + (a.z + a.w) + pb1[j];
        h1s[r * 388 + j] = fmaxf(v, 0.f);
    }
    __syncthreads();

    for (int u = t; u < 1536; u += 256) {
        int o = u >> 1, r = u & 1;
        float4 a = make_float4(0, 0, 0, 0);
        for (int k = 0; k < 384; k += 4) {
            float4 wv = *(const float4*)&pW2[(size_t)o * 384 + k];
            float4 h = *(const float4*)&h1s[r * 388 + k];
            a.x = fmaf(wv.x, h.x, a.x); a.y = fmaf(wv.y, h.y, a.y);
            a.z = fmaf(wv.z, h.z, a.z); a.w = fmaf(wv.w, h.w, a.w);
        }
        xt[r * 772 + o] = (a.x + a.y) + (a.z + a.w) + pb2[o];
    }
    __syncthreads();

    for (int r = 0; r < 2; r++) {
        float s1 = 0.f, s2 = 0.f;
        for (int o = t; o < 768; o += 256) { float v = xt[r * 772 + o]; s1 += v; s2 += v * v; }
#pragma unroll
        for (int off2 = 32; off2 >= 1; off2 >>= 1) {
            s1 += __shfl_down(s1, off2, 64);
            s2 += __shfl_down(s2, off2, 64);
        }
        int lane = t & 63, wid = t >> 6;
        if (lane == 0) { red[wid * 2] = s1; red[wid * 2 + 1] = s2; }
        __syncthreads();
        float S1 = red[0] + red[2] + red[4] + red[6];
        float S2 = red[1] + red[3] + red[5] + red[7];
        float mu = S1 / 768.0f;
        float var = S2 / 768.0f - mu * mu;
        float inv = rsqrtf(var + 1e-5f);
        float* dst = out + ((size_t)b * 40 + pr * 2 + r) * 768;
        for (int o = t; o < 768; o += 256) {
            float v = xt[r * 772 + o];
            dst[o] = (v - mu) * inv * lng[o] + lnb[o];
        }
        __syncthreads();
    }
}

extern "C" void kernel_launch(void* const* d_in, const int* in_sizes, int n_in,
                              void* d_out, int out_size, void* d_ws, size_t ws_size,
                              hipStream_t stream) {
    const float* feat   = (const float*)d_in[0];
    const float* coords = (const float*)d_in[1];
    const float* gW1 = (const float*)d_in[2],  *gb1 = (const float*)d_in[3];
    const float* gW2 = (const float*)d_in[4],  *gb2 = (const float*)d_in[5];
    const float* cW1 = (const float*)d_in[6],  *cb1 = (const float*)d_in[7];
    const float* cW2 = (const float*)d_in[8],  *cb2 = (const float*)d_in[9];
    const float* dW1 = (const float*)d_in[10], *db1 = (const float*)d_in[11];
    const float* dW2 = (const float*)d_in[12], *db2 = (const float*)d_in[13];
    const float* pW1 = (const float*)d_in[14], *pb1 = (const float*)d_in[15];
    const float* pW2 = (const float*)d_in[16], *pb2 = (const float*)d_in[17];
    const float* lng = (const float*)d_in[18], *lnb = (const float*)d_in[19];
    float* out = (float*)d_out;

    int*   idx_all    = (int*)d_ws;               // 896 ints
    float* safety_all = (float*)d_ws + 896;       // 768 floats used
    float* final_all  = (float*)d_ws + 1792;      // 896 floats

    fps_kernel<<<2, 512, 0, stream>>>(coords, idx_all, safety_all);
    score_kernel<<<112, 256, 0, stream>>>(feat, coords, gW1, gb1, gW2, gb2, cW1, cb1, cW2, cb2,
                                          dW1, db1, dW2, db2, idx_all, safety_all, final_all);
    final_kernel<<<40, 256, 0, stream>>>(feat, idx_all, final_all, pW1, pb1, pW2, pb2, lng, lnb, out);
}

// Round 7
// 677.124 us; speedup vs baseline: 1.0886x; 1.0886x over previous
//
#include <hip/hip_runtime.h>
#include <math.h>

#define N_PTS 8192
#define D_FEAT 768

// ---- wave64 reductions via DPP (row_shr 1,2,4,8 + row_bcast15, row_bcast31) ----
__device__ __forceinline__ float wred_max_f32(float x) {   // x >= 0 required (identity 0)
    int v = __float_as_int(x), o;
    o = __builtin_amdgcn_update_dpp(0, v, 0x111, 0xf, 0xf, false); v = __float_as_int(fmaxf(__int_as_float(v), __int_as_float(o)));
    o = __builtin_amdgcn_update_dpp(0, v, 0x112, 0xf, 0xf, false); v = __float_as_int(fmaxf(__int_as_float(v), __int_as_float(o)));
    o = __builtin_amdgcn_update_dpp(0, v, 0x114, 0xf, 0xf, false); v = __float_as_int(fmaxf(__int_as_float(v), __int_as_float(o)));
    o = __builtin_amdgcn_update_dpp(0, v, 0x118, 0xf, 0xf, false); v = __float_as_int(fmaxf(__int_as_float(v), __int_as_float(o)));
    o = __builtin_amdgcn_update_dpp(0, v, 0x142, 0xa, 0xf, false); v = __float_as_int(fmaxf(__int_as_float(v), __int_as_float(o)));
    o = __builtin_amdgcn_update_dpp(0, v, 0x143, 0xc, 0xf, false); v = __float_as_int(fmaxf(__int_as_float(v), __int_as_float(o)));
    return __int_as_float(__builtin_amdgcn_readlane(v, 63));
}
__device__ __forceinline__ int wred_min_i32(int x) {       // x >= 0 (identity INT_MAX)
    int v = x, o;
    o = __builtin_amdgcn_update_dpp(0x7fffffff, v, 0x111, 0xf, 0xf, false); v = (o < v) ? o : v;
    o = __builtin_amdgcn_update_dpp(0x7fffffff, v, 0x112, 0xf, 0xf, false); v = (o < v) ? o : v;
    o = __builtin_amdgcn_update_dpp(0x7fffffff, v, 0x114, 0xf, 0xf, false); v = (o < v) ? o : v;
    o = __builtin_amdgcn_update_dpp(0x7fffffff, v, 0x118, 0xf, 0xf, false); v = (o < v) ? o : v;
    o = __builtin_amdgcn_update_dpp(0x7fffffff, v, 0x142, 0xa, 0xf, false); v = (o < v) ? o : v;
    o = __builtin_amdgcn_update_dpp(0x7fffffff, v, 0x143, 0xc, 0xf, false); v = (o < v) ? o : v;
    return __builtin_amdgcn_readlane(v, 63);
}
__device__ __forceinline__ float wred_add_f32(float x) {   // identity 0
    int v = __float_as_int(x), o;
    o = __builtin_amdgcn_update_dpp(0, v, 0x111, 0xf, 0xf, false); v = __float_as_int(__int_as_float(v) + __int_as_float(o));
    o = __builtin_amdgcn_update_dpp(0, v, 0x112, 0xf, 0xf, false); v = __float_as_int(__int_as_float(v) + __int_as_float(o));
    o = __builtin_amdgcn_update_dpp(0, v, 0x114, 0xf, 0xf, false); v = __float_as_int(__int_as_float(v) + __int_as_float(o));
    o = __builtin_amdgcn_update_dpp(0, v, 0x118, 0xf, 0xf, false); v = __float_as_int(__int_as_float(v) + __int_as_float(o));
    o = __builtin_amdgcn_update_dpp(0, v, 0x142, 0xa, 0xf, false); v = __float_as_int(__int_as_float(v) + __int_as_float(o));
    o = __builtin_amdgcn_update_dpp(0, v, 0x143, 0xc, 0xf, false); v = __float_as_int(__int_as_float(v) + __int_as_float(o));
    return __int_as_float(__builtin_amdgcn_readlane(v, 63));
}

// u64 max-merge DPP step on (hi,lo) pair. identity (0,0) loses to any real key.
#define DPP64_MAX_STEP(ctrl, rmask)                                                       \
    {                                                                                     \
        unsigned ohi = (unsigned)__builtin_amdgcn_update_dpp(0, (int)hi, ctrl, rmask, 0xf, false); \
        unsigned olo = (unsigned)__builtin_amdgcn_update_dpp(0, (int)lo, ctrl, rmask, 0xf, false); \
        bool gt = (ohi > hi) || ((ohi == hi) && (olo > lo));                              \
        hi = gt ? ohi : hi;                                                               \
        lo = gt ? olo : lo;                                                               \
    }

// ---------------- FPS + global/component safety: one block per batch ----------------
// ROUND 7: issue-bound per r6 counters (VALUBusy ~65% of active CUs).
// 4 waves x 32 pts/thread (was 8 x 16): per-iteration reduce machinery paid 4x
// not 8x -> per-SIMD issue ~halves. Owner-stash removed: winner coords via one
// uniform global load (fbi is readlane-uniform -> scalar path, L1/L2-hot).
__global__ __launch_bounds__(256, 1) __attribute__((amdgpu_waves_per_eu(1)))
void fps_kernel(const float* __restrict__ coords,
                int* __restrict__ idx_all,
                float* __restrict__ safety_all) {
#pragma clang fp contract(off)
    const int b = blockIdx.x;         // 0..1
    const int t = threadIdx.x;
    const float* cb = coords + (size_t)b * N_PTS * 3;

    float px[32], py[32], pz[32], m2[32];
#pragma unroll
    for (int k = 0; k < 32; k++) {
        int p = t + k * 256;
        px[k] = cb[p * 3 + 0];
        py[k] = cb[p * 3 + 1];
        pz[k] = cb[p * 3 + 2];
        m2[k] = INFINITY;
    }
    __shared__ unsigned long long skey[2][4];
    __shared__ int sel[256];
    __shared__ float r1s[4], r2s[4];
    if (t == 0) sel[0] = 0;
    float lx = cb[0], ly = cb[1], lz = cb[2];   // center 0 (uniform broadcast load)
    __syncthreads();

    const int lane = t & 63, w = t >> 6;
    for (int i = 1; i < 256; i++) {
        // --- branch-free d2-domain update: 9 VALU/pt, fully pipelineable ---
#pragma unroll
        for (int k = 0; k < 32; k++) {
            float dx = px[k] - lx, dy = py[k] - ly, dz = pz[k] - lz;
            float d2 = dx * dx + dy * dy + dz * dz;   // contract off: numpy op order
            m2[k] = fminf(m2[k], d2);
        }
        // --- per-thread max via balanced fmaxf tree (compiler forms v_max3) ---
        float t0[16];
#pragma unroll
        for (int k = 0; k < 16; k++) t0[k] = fmaxf(m2[k], m2[k + 16]);
#pragma unroll
        for (int k = 0; k < 8; k++) t0[k] = fmaxf(t0[k], t0[k + 8]);
#pragma unroll
        for (int k = 0; k < 4; k++) t0[k] = fmaxf(t0[k], t0[k + 4]);
        float c2 = fmaxf(fmaxf(t0[0], t0[1]), fmaxf(t0[2], t0[3]));
        // --- first index achieving c2: parallel match + min-tree (v_min3) ---
        int ci[16];
#pragma unroll
        for (int k = 0; k < 16; k++) {
            int a = (m2[k] == c2) ? k : 0x7fff;
            int bb = (m2[k + 16] == c2) ? (k + 16) : 0x7fff;
            ci[k] = (a < bb) ? a : bb;
        }
#pragma unroll
        for (int k = 0; k < 8; k++) ci[k] = (ci[k] < ci[k + 8]) ? ci[k] : ci[k + 8];
#pragma unroll
        for (int k = 0; k < 4; k++) ci[k] = (ci[k] < ci[k + 4]) ? ci[k] : ci[k + 4];
        int c01 = (ci[0] < ci[1]) ? ci[0] : ci[1];
        int c23 = (ci[2] < ci[3]) ? ci[2] : ci[3];
        int bk = (c01 < c23) ? c01 : c23;
        // sqrt-collapse guard: >=2 entries within relative 5e-7 band of c2 ->
        // rounded sqrts could tie across distinct d2 -> rare exact path.
        float thi = c2 * 0.9999995f;
        int ncnt = 0;
#pragma unroll
        for (int k = 0; k < 32; k++) ncnt += (m2[k] >= thi) ? 1 : 0;
        float smax;
        if (__any(ncnt >= 2)) {       // rare wave-uniform slow path (exact)
            float sd[32];
#pragma unroll
            for (int k = 0; k < 32; k++) sd[k] = sqrtf(m2[k]);
            smax = sd[0]; bk = 0;
#pragma unroll
            for (int k = 1; k < 32; k++) if (sd[k] > smax) { smax = sd[k]; bk = k; }
        } else {
            smax = sqrtf(c2);         // one correctly-rounded sqrt per thread
        }
        int bi = t + bk * 256;
        // --- wave reduce on packed u64 key: (value desc, index asc) ---
        unsigned hi = __float_as_uint(smax);
        unsigned lo = 0xFFFFFFFFu - (unsigned)bi;
        DPP64_MAX_STEP(0x111, 0xf)    // row_shr1
        DPP64_MAX_STEP(0x112, 0xf)    // row_shr2
        DPP64_MAX_STEP(0x114, 0xf)    // row_shr4
        DPP64_MAX_STEP(0x118, 0xf)    // row_shr8
        DPP64_MAX_STEP(0x142, 0xa)    // row_bcast15
        DPP64_MAX_STEP(0x143, 0xc)    // row_bcast31
        if (lane == 63) {
            skey[i & 1][w] = ((unsigned long long)hi << 32) | lo;
        }
        __syncthreads();   // LDS-only before barrier -> cheap lgkm drain
        const int par = i & 1;
        // --- block combine over 4 wave records: 1 ds_read_b64 + 2 DPP steps ---
        unsigned long long k8 = skey[par][lane & 3];
        {
            unsigned hi = (unsigned)(k8 >> 32), lo = (unsigned)k8;
            DPP64_MAX_STEP(0x111, 0xf)
            DPP64_MAX_STEP(0x112, 0xf)   // lane 3 = max of records 0..3
            k8 = ((unsigned long long)(unsigned)__builtin_amdgcn_readlane((int)hi, 3) << 32)
               | (unsigned)__builtin_amdgcn_readlane((int)lo, 3);
        }
        int fbi = (int)(0xFFFFFFFFu - (unsigned)(k8 & 0xFFFFFFFFu));   // uniform (SGPR)
        // winner coords: one uniform load (L1/L2-hot; replaces owner-stash select)
        lx = cb[fbi * 3 + 0];
        ly = cb[fbi * 3 + 1];
        lz = cb[fbi * 3 + 2];
        // zero the picked point (branch-free; kk uniform)
        {
            bool own = (t == (fbi & 255));
            int kk = fbi >> 8;
#pragma unroll
            for (int k = 0; k < 32; k++) m2[k] = (own && (kk == k)) ? 0.f : m2[k];
        }
        if (t == 0) sel[i] = fbi;     // LDS only
    }

    // ---- tail: write indices once (oc/od are prefixes of og) ----
    __syncthreads();
    {
        int v = sel[t];
        idx_all[b * 256 + t] = v;                    // og
        if (t < 128) idx_all[512 + b * 128 + t] = v; // oc
        if (t < 64)  idx_all[768 + b * 64 + t] = v;  // od
    }

    // ---- tail: global & component safety (z already in registers) ----
    float s1 = 0.f, s2 = 0.f;
#pragma unroll
    for (int k = 0; k < 32; k++) { s1 += pz[k]; s2 += pz[k] * pz[k]; }
    s1 = wred_add_f32(s1);
    s2 = wred_add_f32(s2);
    if (lane == 0) { r1s[w] = s1; r2s[w] = s2; }
    __syncthreads();
    float S1 = r1s[0] + r1s[1] + r1s[2] + r1s[3];
    float S2 = r2s[0] + r2s[1] + r2s[2] + r2s[3];
    float mean = S1 / 8192.0f;
    float var1 = (S2 - S1 * S1 / 8192.0f) / 8191.0f;     // ddof=1
    float scomp = 1.0f + expf(-var1 / 0.1f) * 0.9f;      // component safety
    {
        int p = sel[t];
        float z = cb[p * 3 + 2];
        safety_all[b * 256 + t] = 1.0f + (1.0f / (1.0f + expf(-((z - mean) / 5.0f)))) * 0.95f;
    }
    if (t < 128) safety_all[512 + b * 128 + t] = scomp;
}

// ---------------- per-scale score MLP (+ detail density folded in) ----------------
__global__ __launch_bounds__(256) void score_kernel(
    const float* __restrict__ feat, const float* __restrict__ coords,
    const float* __restrict__ gW1, const float* __restrict__ gb1,
    const float* __restrict__ gW2, const float* __restrict__ gb2,
    const float* __restrict__ cW1, const float* __restrict__ cb1,
    const float* __restrict__ cW2, const float* __restrict__ cb2,
    const float* __restrict__ dW1, const float* __restrict__ db1,
    const float* __restrict__ dW2, const float* __restrict__ db2,
    const int* __restrict__ idx_all, const float* __restrict__ safety_all,
    float* __restrict__ final_all) {
    int bid = blockIdx.x;
    int b, c0, C, S, off;
    const float *W1, *b1, *W2, *b2;
    if (bid < 64)      { C = 256; S = 16; W1 = gW1; b1 = gb1; W2 = gW2; b2 = gb2; b = bid >> 5; c0 = (bid & 31) * 8; off = 0; }
    else if (bid < 96) { int r = bid - 64; C = 128; S = 16; W1 = cW1; b1 = cb1; W2 = cW2; b2 = cb2; b = r >> 4; c0 = (r & 15) * 8; off = 512; }
    else               { int r = bid - 96; C = 64;  S = 8;  W1 = dW1; b1 = db1; W2 = dW2; b2 = db2; b = r >> 3; c0 = (r & 7) * 8; off = 768; }
    const bool isdet = (bid >= 96);

    __shared__ float xt[8 * 772];
    __shared__ float h1s[8 * 260];
    __shared__ float ps[8 * 16];
    __shared__ int pid[8];
    __shared__ float dpart[4][8];
    __shared__ float sdens[8];
    const int t = threadIdx.x;
    if (t < 8) pid[t] = idx_all[off + b * C + c0 + t];
    __syncthreads();

    if (isdet) {
#pragma clang fp contract(off)
        float cx[8], cy[8], cz[8], cc[8];
#pragma unroll
        for (int c = 0; c < 8; c++) {
            const float* cp = coords + ((size_t)b * N_PTS + pid[c]) * 3;
            cx[c] = cp[0]; cy[c] = cp[1]; cz[c] = cp[2];
            cc[c] = cx[c] * cx[c] + cy[c] * cy[c] + cz[c] * cz[c];
        }
        int cnt[8];
#pragma unroll
        for (int c = 0; c < 8; c++) cnt[c] = 0;
        const float* cbl = coords + (size_t)b * N_PTS * 3;
        for (int k = 0; k < 32; k++) {
            int q = t + k * 256;
            float x = cbl[q * 3], y = cbl[q * 3 + 1], z = cbl[q * 3 + 2];
            float pp = x * x + y * y + z * z;
#pragma unroll
            for (int c = 0; c < 8; c++) {
                float dot = cx[c] * x + cy[c] * y + cz[c] * z;
                float d2 = (cc[c] + pp) - 2.0f * dot;   // same formula/order as reference
                if (d2 < 0.25f) cnt[c]++;
            }
        }
        int wv = t >> 6;
#pragma unroll
        for (int c = 0; c < 8; c++) {
            float s = wred_add_f32((float)cnt[c]);      // integer counts: exact in f32
            if ((t & 63) == 0) dpart[wv][c] = s;
        }
    }

    for (int r = 0; r < 8; r++) {
        const float* src = feat + ((size_t)b * N_PTS + pid[r]) * D_FEAT;
        for (int c = t; c < 768; c += 256) xt[r * 772 + c] = src[c];
    }
    __syncthreads();
    if (isdet && t < 8) {
        float tot = dpart[0][t] + dpart[1][t] + dpart[2][t] + dpart[3][t];
        sdens[t] = 1.0f + (tot / 8192.0f) * 0.95f;
    }

    {
        int rp = t & 3;
        int jg = t >> 2;
        int r0 = rp * 2;
        if (jg * 4 < C) {
            float4 acc0[4], acc1[4];
#pragma unroll
            for (int a = 0; a < 4; a++) { acc0[a] = make_float4(0, 0, 0, 0); acc1[a] = make_float4(0, 0, 0, 0); }
            for (int k = 0; k < 768; k += 4) {
                float4 x0 = *(const float4*)&xt[r0 * 772 + k];
                float4 x1 = *(const float4*)&xt[(r0 + 1) * 772 + k];
#pragma unroll
                for (int a = 0; a < 4; a++) {
                    int j = jg * 4 + a;
                    float4 wv = *(const float4*)&W1[(size_t)j * 768 + k];
                    acc0[a].x = fmaf(wv.x, x0.x, acc0[a].x); acc0[a].y = fmaf(wv.y, x0.y, acc0[a].y);
                    acc0[a].z = fmaf(wv.z, x0.z, acc0[a].z); acc0[a].w = fmaf(wv.w, x0.w, acc0[a].w);
                    acc1[a].x = fmaf(wv.x, x1.x, acc1[a].x); acc1[a].y = fmaf(wv.y, x1.y, acc1[a].y);
                    acc1[a].z = fmaf(wv.z, x1.z, acc1[a].z); acc1[a].w = fmaf(wv.w, x1.w, acc1[a].w);
                }
            }
#pragma unroll
            for (int a = 0; a < 4; a++) {
                int j = jg * 4 + a;
                float bb = b1[j];
                float v0 = (acc0[a].x + acc0[a].y) + (acc0[a].z + acc0[a].w) + bb;
                float v1 = (acc1[a].x + acc1[a].y) + (acc1[a].z + acc1[a].w) + bb;
                h1s[r0 * 260 + j]       = fmaxf(v0, 0.f);
                h1s[(r0 + 1) * 260 + j] = fmaxf(v1, 0.f);
            }
        }
    }
    __syncthreads();

    if (t < 8 * S) {
        int r = t / S, s = t % S;
        float4 a = make_float4(0, 0, 0, 0);
        for (int k = 0; k < C; k += 4) {
            float4 wv = *(const float4*)&W2[s * C + k];
            float4 h = *(const float4*)&h1s[r * 260 + k];
            a.x = fmaf(wv.x, h.x, a.x); a.y = fmaf(wv.y, h.y, a.y);
            a.z = fmaf(wv.z, h.z, a.z); a.w = fmaf(wv.w, h.w, a.w);
        }
        float logit = (a.x + a.y) + (a.z + a.w) + b2[s];
        ps[r * 16 + s] = 1.0f / (1.0f + expf(-logit));
    }
    __syncthreads();
    if (t < 8) {
        float m = 0.f;
        for (int s = 0; s < S; s++) m += ps[t * 16 + s];
        m /= (float)S;
        float saf = isdet ? sdens[t] : safety_all[off + b * C + c0 + t];
        final_all[off + b * C + c0 + t] = m * saf;
    }
}

// ---------------- final MLP + LayerNorm, with per-block redundant top-k ----------------
__global__ __launch_bounds__(256) void final_kernel(
    const float* __restrict__ feat, const int* __restrict__ idx_all,
    const float* __restrict__ final_all,
    const float* __restrict__ pW1, const float* __restrict__ pb1,
    const float* __restrict__ pW2, const float* __restrict__ pb2,
    const float* __restrict__ lng, const float* __restrict__ lnb,
    float* __restrict__ out) {
    int bid = blockIdx.x;               // 40 blocks
    int b = bid / 20, pr = bid % 20;
    int t = threadIdx.x;
    __shared__ float xt[2 * 772];
    __shared__ float h1s[2 * 388];
    __shared__ float red[16];
    __shared__ int tokp[2];

    int scale = (pr < 8) ? 0 : (pr < 16) ? 1 : 2;
    int C    = (scale == 0) ? 256 : (scale == 1) ? 128 : 64;
    int off  = (scale == 0) ? 0 : (scale == 1) ? 512 : 768;
    int base = (scale == 0) ? 0 : (scale == 1) ? 8 : 16;   // in block units
    int r0 = (pr - base) * 2;           // rank of first token within scale

    if (t < 64) {                       // wave 0 does the top-k
        float v[4];
#pragma unroll
        for (int j = 0; j < 4; j++) {
            int ii = t + j * 64;
            v[j] = (ii < C) ? final_all[off + b * C + ii] : -INFINITY;
        }
        for (int s = 0; s <= r0 + 1; s++) {
            float bd = v[0]; int bj = 0;
#pragma unroll
            for (int j = 1; j < 4; j++) if (v[j] > bd) { bd = v[j]; bj = j; }
            int bi2 = t + bj * 64;
            float m = wred_max_f32(bd);          // scores > 0, identity 0 safe
            int cand = (bd == m) ? bi2 : 0x7fffffff;
            int wi = wred_min_i32(cand);         // first-index tie-break = lax.top_k
            if (t == (wi & 63)) {
#pragma unroll
                for (int j = 0; j < 4; j++) if (j == (wi >> 6)) v[j] = -INFINITY;
            }
            if (t == 0) {
                if (s == r0)     tokp[0] = idx_all[off + b * C + wi];
                if (s == r0 + 1) tokp[1] = idx_all[off + b * C + wi];
            }
        }
    }
    __syncthreads();

    for (int r = 0; r < 2; r++) {
        int p = tokp[r];
        const float* src = feat + ((size_t)b * N_PTS + p) * D_FEAT;
        for (int c = t; c < 768; c += 256) xt[r * 772 + c] = src[c];
    }
    __syncthreads();

    for (int u = t; u < 768; u += 256) {
        int j = u >> 1, r = u & 1;
        float4 a = make_float4(0, 0, 0, 0);
        for (int k = 0; k < 768; k += 4) {
            float4 wv = *(const float4*)&pW1[(size_t)j * 768 + k];
            float4 x = *(const float4*)&xt[r * 772 + k];
            a.x = fmaf(wv.x, x.x, a.x); a.y = fmaf(wv.y, x.y, a.y);
            a.z = fmaf(wv.z, x.z, a.z); a.w = fmaf(wv.w, x.w, a.w);
        }
        float v = (a.x + a.y) + (a.z + a.w) + pb1[j];
        h1s[r * 388 + j] = fmaxf(v, 0.f);
    }
    __syncthreads();

    for (int u = t; u < 1536; u += 256) {
        int o = u >> 1, r = u & 1;
        float4 a = make_float4(0, 0, 0, 0);
        for (int k = 0; k < 384; k += 4) {
            float4 wv = *(const float4*)&pW2[(size_t)o * 384 + k];
            float4 h = *(const float4*)&h1s[r * 388 + k];
            a.x = fmaf(wv.x, h.x, a.x); a.y = fmaf(wv.y, h.y, a.y);
            a.z = fmaf(wv.z, h.z, a.z); a.w = fmaf(wv.w, h.w, a.w);
        }
        xt[r * 772 + o] = (a.x + a.y) + (a.z + a.w) + pb2[o];
    }
    __syncthreads();

    for (int r = 0; r < 2; r++) {
        float s1 = 0.f, s2 = 0.f;
        for (int o = t; o < 768; o += 256) { float v = xt[r * 772 + o]; s1 += v; s2 += v * v; }
#pragma unroll
        for (int off2 = 32; off2 >= 1; off2 >>= 1) {
            s1 += __shfl_down(s1, off2, 64);
            s2 += __shfl_down(s2, off2, 64);
        }
        int lane = t & 63, wid = t >> 6;
        if (lane == 0) { red[wid * 2] = s1; red[wid * 2 + 1] = s2; }
        __syncthreads();
        float S1 = red[0] + red[2] + red[4] + red[6];
        float S2 = red[1] + red[3] + red[5] + red[7];
        float mu = S1 / 768.0f;
        float var = S2 / 768.0f - mu * mu;
        float inv = rsqrtf(var + 1e-5f);
        float* dst = out + ((size_t)b * 40 + pr * 2 + r) * 768;
        for (int o = t; o < 768; o += 256) {
            float v = xt[r * 772 + o];
            dst[o] = (v - mu) * inv * lng[o] + lnb[o];
        }
        __syncthreads();
    }
}

extern "C" void kernel_launch(void* const* d_in, const int* in_sizes, int n_in,
                              void* d_out, int out_size, void* d_ws, size_t ws_size,
                              hipStream_t stream) {
    const float* feat   = (const float*)d_in[0];
    const float* coords = (const float*)d_in[1];
    const float* gW1 = (const float*)d_in[2],  *gb1 = (const float*)d_in[3];
    const float* gW2 = (const float*)d_in[4],  *gb2 = (const float*)d_in[5];
    const float* cW1 = (const float*)d_in[6],  *cb1 = (const float*)d_in[7];
    const float* cW2 = (const float*)d_in[8],  *cb2 = (const float*)d_in[9];
    const float* dW1 = (const float*)d_in[10], *db1 = (const float*)d_in[11];
    const float* dW2 = (const float*)d_in[12], *db2 = (const float*)d_in[13];
    const float* pW1 = (const float*)d_in[14], *pb1 = (const float*)d_in[15];
    const float* pW2 = (const float*)d_in[16], *pb2 = (const float*)d_in[17];
    const float* lng = (const float*)d_in[18], *lnb = (const float*)d_in[19];
    float* out = (float*)d_out;

    int*   idx_all    = (int*)d_ws;               // 896 ints
    float* safety_all = (float*)d_ws + 896;       // 768 floats used
    float* final_all  = (float*)d_ws + 1792;      // 896 floats

    fps_kernel<<<2, 256, 0, stream>>>(coords, idx_all, safety_all);
    score_kernel<<<112, 256, 0, stream>>>(feat, coords, gW1, gb1, gW2, gb2, cW1, cb1, cW2, cb2,
                                          dW1, db1, dW2, db2, idx_all, safety_all, final_all);
    final_kernel<<<40, 256, 0, stream>>>(feat, idx_all, final_all, pW1, pb1, pW2, pb2, lng, lnb, out);
}

// Round 8
// 618.726 us; speedup vs baseline: 1.1913x; 1.0944x over previous
//
#include <hip/hip_runtime.h>
#include <math.h>

#define N_PTS 8192
#define D_FEAT 768

// ---- wave64 reductions via DPP (row_shr 1,2,4,8 + row_bcast15, row_bcast31) ----
__device__ __forceinline__ float wred_max_f32(float x) {   // x >= 0 required (identity 0)
    int v = __float_as_int(x), o;
    o = __builtin_amdgcn_update_dpp(0, v, 0x111, 0xf, 0xf, false); v = __float_as_int(fmaxf(__int_as_float(v), __int_as_float(o)));
    o = __builtin_amdgcn_update_dpp(0, v, 0x112, 0xf, 0xf, false); v = __float_as_int(fmaxf(__int_as_float(v), __int_as_float(o)));
    o = __builtin_amdgcn_update_dpp(0, v, 0x114, 0xf, 0xf, false); v = __float_as_int(fmaxf(__int_as_float(v), __int_as_float(o)));
    o = __builtin_amdgcn_update_dpp(0, v, 0x118, 0xf, 0xf, false); v = __float_as_int(fmaxf(__int_as_float(v), __int_as_float(o)));
    o = __builtin_amdgcn_update_dpp(0, v, 0x142, 0xa, 0xf, false); v = __float_as_int(fmaxf(__int_as_float(v), __int_as_float(o)));
    o = __builtin_amdgcn_update_dpp(0, v, 0x143, 0xc, 0xf, false); v = __float_as_int(fmaxf(__int_as_float(v), __int_as_float(o)));
    return __int_as_float(__builtin_amdgcn_readlane(v, 63));
}
__device__ __forceinline__ int wred_min_i32(int x) {       // x >= 0 (identity INT_MAX)
    int v = x, o;
    o = __builtin_amdgcn_update_dpp(0x7fffffff, v, 0x111, 0xf, 0xf, false); v = (o < v) ? o : v;
    o = __builtin_amdgcn_update_dpp(0x7fffffff, v, 0x112, 0xf, 0xf, false); v = (o < v) ? o : v;
    o = __builtin_amdgcn_update_dpp(0x7fffffff, v, 0x114, 0xf, 0xf, false); v = (o < v) ? o : v;
    o = __builtin_amdgcn_update_dpp(0x7fffffff, v, 0x118, 0xf, 0xf, false); v = (o < v) ? o : v;
    o = __builtin_amdgcn_update_dpp(0x7fffffff, v, 0x142, 0xa, 0xf, false); v = (o < v) ? o : v;
    o = __builtin_amdgcn_update_dpp(0x7fffffff, v, 0x143, 0xc, 0xf, false); v = (o < v) ? o : v;
    return __builtin_amdgcn_readlane(v, 63);
}
__device__ __forceinline__ float wred_add_f32(float x) {   // identity 0
    int v = __float_as_int(x), o;
    o = __builtin_amdgcn_update_dpp(0, v, 0x111, 0xf, 0xf, false); v = __float_as_int(__int_as_float(v) + __int_as_float(o));
    o = __builtin_amdgcn_update_dpp(0, v, 0x112, 0xf, 0xf, false); v = __float_as_int(__int_as_float(v) + __int_as_float(o));
    o = __builtin_amdgcn_update_dpp(0, v, 0x114, 0xf, 0xf, false); v = __float_as_int(__int_as_float(v) + __int_as_float(o));
    o = __builtin_amdgcn_update_dpp(0, v, 0x118, 0xf, 0xf, false); v = __float_as_int(__int_as_float(v) + __int_as_float(o));
    o = __builtin_amdgcn_update_dpp(0, v, 0x142, 0xa, 0xf, false); v = __float_as_int(__int_as_float(v) + __int_as_float(o));
    o = __builtin_amdgcn_update_dpp(0, v, 0x143, 0xc, 0xf, false); v = __float_as_int(__int_as_float(v) + __int_as_float(o));
    return __int_as_float(__builtin_amdgcn_readlane(v, 63));
}

// u64 max-merge DPP step: compiler lowers the compare to one v_cmp_lt_u64.
// identity 0 loses to any real key (keys always have lo = ~idx > 0).
#define DPP64_STEP(cur, ctrl, rmask)                                                        \
    {                                                                                       \
        unsigned _h = (unsigned)__builtin_amdgcn_update_dpp(0, (int)(unsigned)((cur) >> 32), ctrl, rmask, 0xf, false); \
        unsigned _l = (unsigned)__builtin_amdgcn_update_dpp(0, (int)(unsigned)(cur), ctrl, rmask, 0xf, false);         \
        unsigned long long _o = ((unsigned long long)_h << 32) | _l;                        \
        cur = (_o > (cur)) ? _o : (cur);                                                    \
    }

// ---------------- FPS + global/component safety: one block per batch ----------------
// ROUND 8 deltas vs r7 (both exact):
//  - zero-select removed: the new center's coords are bit-identical to the
//    winner's stored coords, so next update computes d2 = 0 exactly and
//    fminf(m2,0)=0 reproduces dist.at[nxt].set(0.0) before the next argmax.
//  - winner coords via speculative 12-lane load of all 4 candidates issued
//    before the combine, then readlane -> removes the dependent uniform load.
__global__ __launch_bounds__(256, 1) __attribute__((amdgpu_waves_per_eu(1)))
void fps_kernel(const float* __restrict__ coords,
                int* __restrict__ idx_all,
                float* __restrict__ safety_all) {
#pragma clang fp contract(off)
    const int b = blockIdx.x;         // 0..1
    const int t = threadIdx.x;
    const float* cb = coords + (size_t)b * N_PTS * 3;

    float px[32], py[32], pz[32], m2[32];
#pragma unroll
    for (int k = 0; k < 32; k++) {
        int p = t + k * 256;
        px[k] = cb[p * 3 + 0];
        py[k] = cb[p * 3 + 1];
        pz[k] = cb[p * 3 + 2];
        m2[k] = INFINITY;
    }
    __shared__ unsigned long long skey[2][4];
    __shared__ int sel[256];
    __shared__ float r1s[4], r2s[4];
    if (t == 0) sel[0] = 0;
    float lx = cb[0], ly = cb[1], lz = cb[2];   // center 0 (uniform broadcast load)
    __syncthreads();

    const int lane = t & 63, w = t >> 6;
    for (int i = 1; i < 256; i++) {
        // --- branch-free d2-domain update: 9 VALU/pt (numpy op order) ---
#pragma unroll
        for (int k = 0; k < 32; k++) {
            float dx = px[k] - lx, dy = py[k] - ly, dz = pz[k] - lz;
            float d2 = dx * dx + dy * dy + dz * dz;
            m2[k] = fminf(m2[k], d2);
        }
        // --- per-thread max via balanced fmaxf tree ---
        float t0[16];
#pragma unroll
        for (int k = 0; k < 16; k++) t0[k] = fmaxf(m2[k], m2[k + 16]);
#pragma unroll
        for (int k = 0; k < 8; k++) t0[k] = fmaxf(t0[k], t0[k + 8]);
#pragma unroll
        for (int k = 0; k < 4; k++) t0[k] = fmaxf(t0[k], t0[k + 4]);
        float c2 = fmaxf(fmaxf(t0[0], t0[1]), fmaxf(t0[2], t0[3]));
        // --- first index achieving c2: parallel match + min tree ---
        int ci[16];
#pragma unroll
        for (int k = 0; k < 16; k++) {
            int a  = (m2[k]      == c2) ? k        : 0x7fff;
            int bb = (m2[k + 16] == c2) ? (k + 16) : 0x7fff;
            ci[k] = (a < bb) ? a : bb;
        }
#pragma unroll
        for (int k = 0; k < 8; k++) ci[k] = min(ci[k], ci[k + 8]);
#pragma unroll
        for (int k = 0; k < 4; k++) ci[k] = min(ci[k], ci[k + 4]);
        int bk = min(min(ci[0], ci[1]), min(ci[2], ci[3]));
        // sqrt-collapse guard: >=2 entries within relative 5e-7 band of c2 ->
        // rounded sqrts could tie across distinct d2 -> rare exact path.
        float thi = c2 * 0.9999995f;
        int ncnt = 0;
#pragma unroll
        for (int k = 0; k < 32; k++) ncnt += (m2[k] >= thi) ? 1 : 0;
        float smax;
        if (__any(ncnt >= 2)) {       // rare wave-uniform slow path (exact)
            float sd[32];
#pragma unroll
            for (int k = 0; k < 32; k++) sd[k] = sqrtf(m2[k]);
            smax = sd[0]; bk = 0;
#pragma unroll
            for (int k = 1; k < 32; k++) if (sd[k] > smax) { smax = sd[k]; bk = k; }
        } else {
            smax = sqrtf(c2);         // one correctly-rounded sqrt per thread
        }
        int bi = t + bk * 256;
        // --- wave reduce on packed u64 key: (value desc, index asc) ---
        unsigned long long key = ((unsigned long long)__float_as_uint(smax) << 32)
                               | (unsigned)(0xFFFFFFFFu - (unsigned)bi);
        DPP64_STEP(key, 0x111, 0xf)    // row_shr1
        DPP64_STEP(key, 0x112, 0xf)    // row_shr2
        DPP64_STEP(key, 0x114, 0xf)    // row_shr4
        DPP64_STEP(key, 0x118, 0xf)    // row_shr8
        DPP64_STEP(key, 0x142, 0xa)    // row_bcast15
        DPP64_STEP(key, 0x143, 0xc)    // row_bcast31
        if (lane == 63) skey[i & 1][w] = key;
        __syncthreads();   // LDS-only before barrier -> cheap lgkm drain
        const int par = i & 1;
        // --- read 4 wave records; speculatively load ALL candidates' coords ---
        unsigned long long k8 = skey[par][lane & 3];
        int cidx = (int)(0xFFFFFFFFu - (unsigned)k8);   // candidate of record lane&3
        float spec = 0.f;
        if (lane < 12) spec = cb[cidx * 3 + (lane >> 2)];   // one load covers 4x xyz
        // --- combine over 4 records (overlaps the load) ---
        DPP64_STEP(k8, 0x111, 0xf)
        DPP64_STEP(k8, 0x112, 0xf)     // lane 3 = max of records 0..3
        unsigned klo = (unsigned)__builtin_amdgcn_readlane((int)(unsigned)k8, 3);
        int fbi = (int)(0xFFFFFFFFu - klo);             // uniform (SGPR)
        int ww = (fbi & 255) >> 6;                      // winning wave / record
        // winner coords from the speculative lanes: rec=ww, comp c at lane c*4+ww
        lx = __int_as_float(__builtin_amdgcn_readlane(__float_as_int(spec), ww));
        ly = __int_as_float(__builtin_amdgcn_readlane(__float_as_int(spec), 4 + ww));
        lz = __int_as_float(__builtin_amdgcn_readlane(__float_as_int(spec), 8 + ww));
        if (t == 0) sel[i] = fbi;     // LDS only
        // NOTE: no explicit zeroing of the winner: next update gives d2=0 exactly.
    }

    // ---- tail: write indices once (oc/od are prefixes of og) ----
    __syncthreads();
    {
        int v = sel[t];
        idx_all[b * 256 + t] = v;                    // og
        if (t < 128) idx_all[512 + b * 128 + t] = v; // oc
        if (t < 64)  idx_all[768 + b * 64 + t] = v;  // od
    }

    // ---- tail: global & component safety (z already in registers) ----
    float s1 = 0.f, s2 = 0.f;
#pragma unroll
    for (int k = 0; k < 32; k++) { s1 += pz[k]; s2 += pz[k] * pz[k]; }
    s1 = wred_add_f32(s1);
    s2 = wred_add_f32(s2);
    if (lane == 0) { r1s[w] = s1; r2s[w] = s2; }
    __syncthreads();
    float S1 = r1s[0] + r1s[1] + r1s[2] + r1s[3];
    float S2 = r2s[0] + r2s[1] + r2s[2] + r2s[3];
    float mean = S1 / 8192.0f;
    float var1 = (S2 - S1 * S1 / 8192.0f) / 8191.0f;     // ddof=1
    float scomp = 1.0f + expf(-var1 / 0.1f) * 0.9f;      // component safety
    {
        int p = sel[t];
        float z = cb[p * 3 + 2];
        safety_all[b * 256 + t] = 1.0f + (1.0f / (1.0f + expf(-((z - mean) / 5.0f)))) * 0.95f;
    }
    if (t < 128) safety_all[512 + b * 128 + t] = scomp;
}

// ---------------- per-scale score MLP (+ detail density folded in) ----------------
__global__ __launch_bounds__(256) void score_kernel(
    const float* __restrict__ feat, const float* __restrict__ coords,
    const float* __restrict__ gW1, const float* __restrict__ gb1,
    const float* __restrict__ gW2, const float* __restrict__ gb2,
    const float* __restrict__ cW1, const float* __restrict__ cb1,
    const float* __restrict__ cW2, const float* __restrict__ cb2,
    const float* __restrict__ dW1, const float* __restrict__ db1,
    const float* __restrict__ dW2, const float* __restrict__ db2,
    const int* __restrict__ idx_all, const float* __restrict__ safety_all,
    float* __restrict__ final_all) {
    int bid = blockIdx.x;
    int b, c0, C, S, off;
    const float *W1, *b1, *W2, *b2;
    if (bid < 64)      { C = 256; S = 16; W1 = gW1; b1 = gb1; W2 = gW2; b2 = gb2; b = bid >> 5; c0 = (bid & 31) * 8; off = 0; }
    else if (bid < 96) { int r = bid - 64; C = 128; S = 16; W1 = cW1; b1 = cb1; W2 = cW2; b2 = cb2; b = r >> 4; c0 = (r & 15) * 8; off = 512; }
    else               { int r = bid - 96; C = 64;  S = 8;  W1 = dW1; b1 = db1; W2 = dW2; b2 = db2; b = r >> 3; c0 = (r & 7) * 8; off = 768; }
    const bool isdet = (bid >= 96);

    __shared__ float xt[8 * 772];
    __shared__ float h1s[8 * 260];
    __shared__ float ps[8 * 16];
    __shared__ int pid[8];
    __shared__ float dpart[4][8];
    __shared__ float sdens[8];
    const int t = threadIdx.x;
    if (t < 8) pid[t] = idx_all[off + b * C + c0 + t];
    __syncthreads();

    if (isdet) {
#pragma clang fp contract(off)
        float cx[8], cy[8], cz[8], cc[8];
#pragma unroll
        for (int c = 0; c < 8; c++) {
            const float* cp = coords + ((size_t)b * N_PTS + pid[c]) * 3;
            cx[c] = cp[0]; cy[c] = cp[1]; cz[c] = cp[2];
            cc[c] = cx[c] * cx[c] + cy[c] * cy[c] + cz[c] * cz[c];
        }
        int cnt[8];
#pragma unroll
        for (int c = 0; c < 8; c++) cnt[c] = 0;
        const float* cbl = coords + (size_t)b * N_PTS * 3;
        for (int k = 0; k < 32; k++) {
            int q = t + k * 256;
            float x = cbl[q * 3], y = cbl[q * 3 + 1], z = cbl[q * 3 + 2];
            float pp = x * x + y * y + z * z;
#pragma unroll
            for (int c = 0; c < 8; c++) {
                float dot = cx[c] * x + cy[c] * y + cz[c] * z;
                float d2 = (cc[c] + pp) - 2.0f * dot;   // same formula/order as reference
                if (d2 < 0.25f) cnt[c]++;
            }
        }
        int wv = t >> 6;
#pragma unroll
        for (int c = 0; c < 8; c++) {
            float s = wred_add_f32((float)cnt[c]);      // integer counts: exact in f32
            if ((t & 63) == 0) dpart[wv][c] = s;
        }
    }

    for (int r = 0; r < 8; r++) {
        const float* src = feat + ((size_t)b * N_PTS + pid[r]) * D_FEAT;
        for (int c = t; c < 768; c += 256) xt[r * 772 + c] = src[c];
    }
    __syncthreads();
    if (isdet && t < 8) {
        float tot = dpart[0][t] + dpart[1][t] + dpart[2][t] + dpart[3][t];
        sdens[t] = 1.0f + (tot / 8192.0f) * 0.95f;
    }

    {
        int rp = t & 3;
        int jg = t >> 2;
        int r0 = rp * 2;
        if (jg * 4 < C) {
            float4 acc0[4], acc1[4];
#pragma unroll
            for (int a = 0; a < 4; a++) { acc0[a] = make_float4(0, 0, 0, 0); acc1[a] = make_float4(0, 0, 0, 0); }
            for (int k = 0; k < 768; k += 4) {
                float4 x0 = *(const float4*)&xt[r0 * 772 + k];
                float4 x1 = *(const float4*)&xt[(r0 + 1) * 772 + k];
#pragma unroll
                for (int a = 0; a < 4; a++) {
                    int j = jg * 4 + a;
                    float4 wv = *(const float4*)&W1[(size_t)j * 768 + k];
                    acc0[a].x = fmaf(wv.x, x0.x, acc0[a].x); acc0[a].y = fmaf(wv.y, x0.y, acc0[a].y);
                    acc0[a].z = fmaf(wv.z, x0.z, acc0[a].z); acc0[a].w = fmaf(wv.w, x0.w, acc0[a].w);
                    acc1[a].x = fmaf(wv.x, x1.x, acc1[a].x); acc1[a].y = fmaf(wv.y, x1.y, acc1[a].y);
                    acc1[a].z = fmaf(wv.z, x1.z, acc1[a].z); acc1[a].w = fmaf(wv.w, x1.w, acc1[a].w);
                }
            }
#pragma unroll
            for (int a = 0; a < 4; a++) {
                int j = jg * 4 + a;
                float bb = b1[j];
                float v0 = (acc0[a].x + acc0[a].y) + (acc0[a].z + acc0[a].w) + bb;
                float v1 = (acc1[a].x + acc1[a].y) + (acc1[a].z + acc1[a].w) + bb;
                h1s[r0 * 260 + j]       = fmaxf(v0, 0.f);
                h1s[(r0 + 1) * 260 + j] = fmaxf(v1, 0.f);
            }
        }
    }
    __syncthreads();

    if (t < 8 * S) {
        int r = t / S, s = t % S;
        float4 a = make_float4(0, 0, 0, 0);
        for (int k = 0; k < C; k += 4) {
            float4 wv = *(const float4*)&W2[s * C + k];
            float4 h = *(const float4*)&h1s[r * 260 + k];
            a.x = fmaf(wv.x, h.x, a.x); a.y = fmaf(wv.y, h.y, a.y);
            a.z = fmaf(wv.z, h.z, a.z); a.w = fmaf(wv.w, h.w, a.w);
        }
        float logit = (a.x + a.y) + (a.z + a.w) + b2[s];
        ps[r * 16 + s] = 1.0f / (1.0f + expf(-logit));
    }
    __syncthreads();
    if (t < 8) {
        float m = 0.f;
        for (int s = 0; s < S; s++) m += ps[t * 16 + s];
        m /= (float)S;
        float saf = isdet ? sdens[t] : safety_all[off + b * C + c0 + t];
        final_all[off + b * C + c0 + t] = m * saf;
    }
}

// ---------------- final MLP + LayerNorm, with per-block redundant top-k ----------------
__global__ __launch_bounds__(256) void final_kernel(
    const float* __restrict__ feat, const int* __restrict__ idx_all,
    const float* __restrict__ final_all,
    const float* __restrict__ pW1, const float* __restrict__ pb1,
    const float* __restrict__ pW2, const float* __restrict__ pb2,
    const float* __restrict__ lng, const float* __restrict__ lnb,
    float* __restrict__ out) {
    int bid = blockIdx.x;               // 40 blocks
    int b = bid / 20, pr = bid % 20;
    int t = threadIdx.x;
    __shared__ float xt[2 * 772];
    __shared__ float h1s[2 * 388];
    __shared__ float red[16];
    __shared__ int tokp[2];

    int scale = (pr < 8) ? 0 : (pr < 16) ? 1 : 2;
    int C    = (scale == 0) ? 256 : (scale == 1) ? 128 : 64;
    int off  = (scale == 0) ? 0 : (scale == 1) ? 512 : 768;
    int base = (scale == 0) ? 0 : (scale == 1) ? 8 : 16;   // in block units
    int r0 = (pr - base) * 2;           // rank of first token within scale

    if (t < 64) {                       // wave 0 does the top-k
        float v[4];
#pragma unroll
        for (int j = 0; j < 4; j++) {
            int ii = t + j * 64;
            v[j] = (ii < C) ? final_all[off + b * C + ii] : -INFINITY;
        }
        for (int s = 0; s <= r0 + 1; s++) {
            float bd = v[0]; int bj = 0;
#pragma unroll
            for (int j = 1; j < 4; j++) if (v[j] > bd) { bd = v[j]; bj = j; }
            int bi2 = t + bj * 64;
            float m = wred_max_f32(bd);          // scores > 0, identity 0 safe
            int cand = (bd == m) ? bi2 : 0x7fffffff;
            int wi = wred_min_i32(cand);         // first-index tie-break = lax.top_k
            if (t == (wi & 63)) {
#pragma unroll
                for (int j = 0; j < 4; j++) if (j == (wi >> 6)) v[j] = -INFINITY;
            }
            if (t == 0) {
                if (s == r0)     tokp[0] = idx_all[off + b * C + wi];
                if (s == r0 + 1) tokp[1] = idx_all[off + b * C + wi];
            }
        }
    }
    __syncthreads();

    for (int r = 0; r < 2; r++) {
        int p = tokp[r];
        const float* src = feat + ((size_t)b * N_PTS + p) * D_FEAT;
        for (int c = t; c < 768; c += 256) xt[r * 772 + c] = src[c];
    }
    __syncthreads();

    for (int u = t; u < 768; u += 256) {
        int j = u >> 1, r = u & 1;
        float4 a = make_float4(0, 0, 0, 0);
        for (int k = 0; k < 768; k += 4) {
            float4 wv = *(const float4*)&pW1[(size_t)j * 768 + k];
            float4 x = *(const float4*)&xt[r * 772 + k];
            a.x = fmaf(wv.x, x.x, a.x); a.y = fmaf(wv.y, x.y, a.y);
            a.z = fmaf(wv.z, x.z, a.z); a.w = fmaf(wv.w, x.w, a.w);
        }
        float v = (a.x + a.y) + (a.z + a.w) + pb1[j];
        h1s[r * 388 + j] = fmaxf(v, 0.f);
    }
    __syncthreads();

    for (int u = t; u < 1536; u += 256) {
        int o = u >> 1, r = u & 1;
        float4 a = make_float4(0, 0, 0, 0);
        for (int k = 0; k < 384; k += 4) {
            float4 wv = *(const float4*)&pW2[(size_t)o * 384 + k];
            float4 h = *(const float4*)&h1s[r * 388 + k];
            a.x = fmaf(wv.x, h.x, a.x); a.y = fmaf(wv.y, h.y, a.y);
            a.z = fmaf(wv.z, h.z, a.z); a.w = fmaf(wv.w, h.w, a.w);
        }
        xt[r * 772 + o] = (a.x + a.y) + (a.z + a.w) + pb2[o];
    }
    __syncthreads();

    for (int r = 0; r < 2; r++) {
        float s1 = 0.f, s2 = 0.f;
        for (int o = t; o < 768; o += 256) { float v = xt[r * 772 + o]; s1 += v; s2 += v * v; }
#pragma unroll
        for (int off2 = 32; off2 >= 1; off2 >>= 1) {
            s1 += __shfl_down(s1, off2, 64);
            s2 += __shfl_down(s2, off2, 64);
        }
        int lane = t & 63, wid = t >> 6;
        if (lane == 0) { red[wid * 2] = s1; red[wid * 2 + 1] = s2; }
        __syncthreads();
        float S1 = red[0] + red[2] + red[4] + red[6];
        float S2 = red[1] + red[3] + red[5] + red[7];
        float mu = S1 / 768.0f;
        float var = S2 / 768.0f - mu * mu;
        float inv = rsqrtf(var + 1e-5f);
        float* dst = out + ((size_t)b * 40 + pr * 2 + r) * 768;
        for (int o = t; o < 768; o += 256) {
            float v = xt[r * 772 + o];
            dst[o] = (v - mu) * inv * lng[o] + lnb[o];
        }
        __syncthreads();
    }
}

extern "C" void kernel_launch(void* const* d_in, const int* in_sizes, int n_in,
                              void* d_out, int out_size, void* d_ws, size_t ws_size,
                              hipStream_t stream) {
    const float* feat   = (const float*)d_in[0];
    const float* coords = (const float*)d_in[1];
    const float* gW1 = (const float*)d_in[2],  *gb1 = (const float*)d_in[3];
    const float* gW2 = (const float*)d_in[4],  *gb2 = (const float*)d_in[5];
    const float* cW1 = (const float*)d_in[6],  *cb1 = (const float*)d_in[7];
    const float* cW2 = (const float*)d_in[8],  *cb2 = (const float*)d_in[9];
    const float* dW1 = (const float*)d_in[10], *db1 = (const float*)d_in[11];
    const float* dW2 = (const float*)d_in[12], *db2 = (const float*)d_in[13];
    const float* pW1 = (const float*)d_in[14], *pb1 = (const float*)d_in[15];
    const float* pW2 = (const float*)d_in[16], *pb2 = (const float*)d_in[17];
    const float* lng = (const float*)d_in[18], *lnb = (const float*)d_in[19];
    float* out = (float*)d_out;

    int*   idx_all    = (int*)d_ws;               // 896 ints
    float* safety_all = (float*)d_ws + 896;       // 768 floats used
    float* final_all  = (float*)d_ws + 1792;      // 896 floats

    fps_kernel<<<2, 256, 0, stream>>>(coords, idx_all, safety_all);
    score_kernel<<<112, 256, 0, stream>>>(feat, coords, gW1, gb1, gW2, gb2, cW1, cb1, cW2, cb2,
                                          dW1, db1, dW2, db2, idx_all, safety_all, final_all);
    final_kernel<<<40, 256, 0, stream>>>(feat, idx_all, final_all, pW1, pb1, pW2, pb2, lng, lnb, out);
}